// Round 11
// baseline (248.199 us; speedup 1.0000x reference)
//
#include <hip/hip_runtime.h>
#include <hip/hip_fp16.h>
#include <math.h>

#define N_NODES 100000
#define N_EDGES 3200000
#define D_IN    128
#define H1      16

#define BSH     8
#define NPB     256                    // nodes per bucket (partition granularity)
#define NB      391                    // ceil(100000/256)
#define CAP     13056                  // eop region capacity (x16; padded fill ~12280)
#define PBLK    512
#define CHUNK   6250                   // N_EDGES / PBLK exact
#define ELS_CAP 12128                  // >= 6250 + 391*15 = 12115, multiple of 16
#define NLINES  (ELS_CAP / 16)         // 758
#define MROWS   64
#define SLOTS   26                     // ceil(CAP/512) register staging slots
#define AELS    5120                   // sorted-src LDS cap per half (MEAN is 4096! +16 sigma)

// eop: NB regions of CAP uints holding packed (src<<8|dloc), runs padded to 64B
// lines with 0xFFFFFFFF sentinels, written as full lines (round-8 fix).
// No global CSR: k_agg1f sorts the region into LDS and aggregates in-kernel.
// Round-10 bug: AELS=4096 == mean half-bucket fill -> ~half of blocks dropped
// edges. AELS must be mean + many sigma (5120).

__global__ __launch_bounds__(512) void k_zero(int* __restrict__ cursor) {
    int t = threadIdx.x;
    if (t < NB) cursor[t] = 0;
}

// ---- partition: rank -> scan -> LDS bucket-sort -> coalesced full-line writeout ----
__global__ __launch_bounds__(512) void k_partition(const int* __restrict__ ei,
                                                   int* __restrict__ cursor,
                                                   unsigned int* __restrict__ eop) {
    __shared__ int h[512];                       // per-bucket counts (pad to 512)
    __shared__ int loff[512];                    // scan -> exclusive local offsets
    __shared__ int resv[NB];                     // global region offsets
    __shared__ unsigned short owner[NLINES];     // line -> bucket
    __shared__ unsigned char rank8[CHUNK];       // per-edge rank in its run (<255)
    __shared__ unsigned int els[ELS_CAP];        // 48.5 KB staging
    int t = threadIdx.x;
    h[t] = 0;
    __syncthreads();
    int c0 = blockIdx.x * CHUNK;
    const int* srcs = ei + c0;
    const int* dsts = ei + N_EDGES + c0;
    for (int i = t; i < CHUNK; i += 512)
        rank8[i] = (unsigned char)atomicAdd(&h[dsts[i] >> BSH], 1);
    __syncthreads();
    int cp = (h[t] + 15) & ~15;                  // run padded to 64B multiple
    loff[t] = cp;
    __syncthreads();
    for (int o = 1; o < 512; o <<= 1) {          // inclusive Hillis-Steele
        int u = (t >= o) ? loff[t - o] : 0;
        __syncthreads();
        loff[t] += u;
        __syncthreads();
    }
    int inc = loff[t];
    int totalpad = loff[511];                    // <= ELS_CAP by construction
    int ex = inc - cp;
    __syncthreads();
    loff[t] = ex;                                // now exclusive
    if (t < NB && cp) {
        resv[t] = atomicAdd(&cursor[t], cp);     // stays 16-aligned
        int l0 = ex >> 4;
        for (int k = 0; k < (cp >> 4); ++k) owner[l0 + k] = (unsigned short)t;
    }
    for (int i = t; i < totalpad; i += 512) els[i] = 0xFFFFFFFFu;   // sentinels
    __syncthreads();
    for (int i = t; i < CHUNK; i += 512) {       // LDS bucket-sort scatter
        int s = srcs[i];
        int d = dsts[i];
        int b = d >> BSH;
        els[loff[b] + (int)rank8[i]] = ((unsigned)s << BSH) | (unsigned)(d & (NPB - 1));
    }
    __syncthreads();
    for (int i = t; i < totalpad; i += 512) {    // coalesced: full 64B lines
        int b   = owner[i >> 4];
        int pos = resv[b] + (i - loff[b]);
        if (pos < CAP)                           // statistically impossible guard
            eop[(size_t)b * CAP + pos] = els[i];
    }
}

// ---- count: half-bucket degree count -> dinv (unblocks pre-scaled mm1) ----
__global__ __launch_bounds__(512) void k_count(const int* __restrict__ cursor,
                                               const unsigned int* __restrict__ eop,
                                               float* __restrict__ dinv) {
    __shared__ int cnt[128];
    int t = threadIdx.x;
    int b = blockIdx.x >> 1, hh = blockIdx.x & 1;
    if (t < 128) cnt[t] = 0;
    __syncthreads();
    int n = cursor[b]; if (n > CAP) n = CAP;
    const unsigned int* reg = eop + (size_t)b * CAP;
    for (int i = t; i < n; i += 512) {
        unsigned int v = reg[i];
        if ((int)v >= 0) {                       // real entry (bit31==0)
            int dloc = v & (NPB - 1);
            if ((dloc >> 7) == hh) atomicAdd(&cnt[dloc & 127], 1);
        }
    }
    __syncthreads();
    if (t < 128) {
        int node = (b << BSH) + (hh << 7) + t;
        if (node < N_NODES) dinv[node] = rsqrtf((float)(cnt[t] + 1));   // +1 self-loop
    }
}

// ---- matmul: wave = 64 rows x 4 cols, x in LDS (pad 129), W uniform loads ----
__global__ __launch_bounds__(256) void k_mm1(const float* __restrict__ x,
                                             const float* __restrict__ W1,
                                             const float* __restrict__ dinv,
                                             __half* __restrict__ h1h) {
    __shared__ float sX[MROWS][D_IN + 1];   // 33 KB
    int t = threadIdx.x;
    int r0 = blockIdx.x * MROWS;
    for (int i = t; i < MROWS * (D_IN / 4); i += 256) {
        int row = i >> 5, c4 = i & 31;
        int grow = r0 + row;
        float4 v = (grow < N_NODES) ? ((const float4*)x)[(size_t)grow * 32 + c4]
                                    : make_float4(0.f, 0.f, 0.f, 0.f);
        sX[row][c4 * 4 + 0] = v.x; sX[row][c4 * 4 + 1] = v.y;
        sX[row][c4 * 4 + 2] = v.z; sX[row][c4 * 4 + 3] = v.w;
    }
    __syncthreads();
    int lane = t & 63;
    int c0 = __builtin_amdgcn_readfirstlane((t >> 6) * 4);
    float a0 = 0.f, a1 = 0.f, a2 = 0.f, a3 = 0.f;
#pragma unroll 4
    for (int d = 0; d < D_IN; ++d) {
        float xv = sX[lane][d];
        a0 = fmaf(xv, W1[d * 16 + c0 + 0], a0);
        a1 = fmaf(xv, W1[d * 16 + c0 + 1], a1);
        a2 = fmaf(xv, W1[d * 16 + c0 + 2], a2);
        a3 = fmaf(xv, W1[d * 16 + c0 + 3], a3);
    }
    int grow = r0 + lane;
    if (grow < N_NODES) {
        float di = dinv[grow];
        __half2* o = (__half2*)(h1h + (size_t)grow * H1 + c0);
        o[0] = __floats2half2_rn(a0 * di, a1 * di);
        o[1] = __floats2half2_rn(a2 * di, a3 * di);
    }
}

// ---- fused build+agg1: register-stage region, sort into LDS, aggregate ----
// Half-bucket block (128 nodes). Packed reg slot: src:17 | rank:7<<17 | dloc:7<<24.
__global__ __launch_bounds__(512) void k_agg1f(const int* __restrict__ cursor,
                                               const unsigned int* __restrict__ eop,
                                               const __half* __restrict__ h1h,
                                               const float* __restrict__ dinv,
                                               const float* __restrict__ b1,
                                               const float* __restrict__ W2,
                                               float2* __restrict__ h2f) {
    __shared__ int cnt[128], off[128];
    __shared__ int els[AELS];            // sorted src list, 20 KB
    int t = threadIdx.x;
    int b = blockIdx.x >> 1, hh = blockIdx.x & 1;
    if (t < 128) cnt[t] = 0;
    __syncthreads();
    int n = cursor[b]; if (n > CAP) n = CAP;
    const unsigned int* reg = eop + (size_t)b * CAP;
    unsigned int vals[SLOTS];
#pragma unroll
    for (int k = 0; k < SLOTS; ++k) {
        int i = t + k * 512;
        unsigned int w = 0xFFFFFFFFu;
        if (i < n) {
            unsigned int v = reg[i];
            if ((int)v >= 0) {
                int dloc = v & (NPB - 1);
                if ((dloc >> 7) == hh) {
                    int r = atomicAdd(&cnt[dloc & 127], 1);    // rank < ~80 (deg max)
                    w = (v >> 8) | ((unsigned)(r & 127) << 17)
                                 | ((unsigned)(dloc & 127) << 24);
                }
            }
        }
        vals[k] = w;
    }
    __syncthreads();
    int val = (t < 128) ? cnt[t] : 0;
    if (t < 128) off[t] = val;
    __syncthreads();
    for (int o = 1; o < 128; o <<= 1) {          // inclusive Hillis-Steele
        int u = 0;
        if (t < 128 && t >= o) u = off[t - o];
        __syncthreads();
        if (t < 128) off[t] += u;
        __syncthreads();
    }
    if (t < 128) off[t] -= val;                  // exclusive
    __syncthreads();
#pragma unroll
    for (int k = 0; k < SLOTS; ++k) {            // scatter srcs into sorted LDS
        unsigned int w = vals[k];
        if (w != 0xFFFFFFFFu) {
            int src  = w & 0x1FFFF;
            int r    = (w >> 17) & 127;
            int dloc = (w >> 24) & 127;
            int p = off[dloc] + r;
            if (p < AELS) els[p] = src;
        }
    }
    __syncthreads();
    // aggregation: 32 groups x 16 lanes; each group handles 4 nodes
    int g = t >> 4, l = t & 15;
    for (int nn = g; nn < 128; nn += 32) {
        int node = (b << BSH) + (hh << 7) + nn;
        if (node >= N_NODES) continue;
        int e = cnt[nn], base = off[nn];
        float acc = 0.f;
        int j = 0;
        for (; j + 4 <= e; j += 4) {
            int s0 = els[base + j],     s1 = els[base + j + 1];
            int s2 = els[base + j + 2], s3 = els[base + j + 3];
            acc += __half2float(h1h[s0 * H1 + l]) + __half2float(h1h[s1 * H1 + l])
                 + __half2float(h1h[s2 * H1 + l]) + __half2float(h1h[s3 * H1 + l]);
        }
        for (; j < e; ++j) acc += __half2float(h1h[els[base + j] * H1 + l]);
        float di = dinv[node];
        float s  = acc + __half2float(h1h[node * H1 + l]);   // + self-loop
        float h  = fmaxf(fmaf(di, s, b1[l]), 0.f);
        float p0 = h * W2[2 * l], p1 = h * W2[2 * l + 1];
#pragma unroll
        for (int o2 = 1; o2 < 16; o2 <<= 1) {
            p0 += __shfl_xor(p0, o2);
            p1 += __shfl_xor(p1, o2);
        }
        if (l == 0) h2f[node] = make_float2(p0 * di, p1 * di);
    }
}

// ---- layer-2 agg: region-direct LDS accumulate + b2 + log_softmax ----
__global__ __launch_bounds__(512) void k_agg2f(const int* __restrict__ cursor,
                                               const unsigned int* __restrict__ eop,
                                               const float2* __restrict__ h2f,
                                               const float* __restrict__ dinv,
                                               const float* __restrict__ b2,
                                               float* __restrict__ out) {
    __shared__ float ax[128], ay[128];
    int t = threadIdx.x;
    int b = blockIdx.x >> 1, hh = blockIdx.x & 1;
    if (t < 128) { ax[t] = 0.f; ay[t] = 0.f; }
    __syncthreads();
    int n = cursor[b]; if (n > CAP) n = CAP;
    const unsigned int* reg = eop + (size_t)b * CAP;
    for (int i = t; i < n; i += 512) {
        unsigned int v = reg[i];
        if ((int)v >= 0) {
            int dloc = v & (NPB - 1);
            if ((dloc >> 7) == hh) {
                float2 m = h2f[v >> 8];
                atomicAdd(&ax[dloc & 127], m.x);
                atomicAdd(&ay[dloc & 127], m.y);
            }
        }
    }
    __syncthreads();
    if (t < 128) {
        int node = (b << BSH) + (hh << 7) + t;
        if (node < N_NODES) {
            float di = dinv[node];
            float2 self = h2f[node];
            float a0 = fmaf(di, ax[t] + self.x, b2[0]);
            float a1 = fmaf(di, ay[t] + self.y, b2[1]);
            float m  = fmaxf(a0, a1);
            float lg = logf(expf(a0 - m) + expf(a1 - m));
            out[2 * node]     = a0 - m - lg;
            out[2 * node + 1] = a1 - m - lg;
        }
    }
}

extern "C" void kernel_launch(void* const* d_in, const int* in_sizes, int n_in,
                              void* d_out, int out_size, void* d_ws, size_t ws_size,
                              hipStream_t stream) {
    const float* x  = (const float*)d_in[0];
    const int*   ei = (const int*)d_in[1];
    const float* W1 = (const float*)d_in[2];
    const float* b1 = (const float*)d_in[3];
    const float* W2 = (const float*)d_in[4];
    const float* b2 = (const float*)d_in[5];
    float* out = (float*)d_out;

    // workspace carve (~25 MB of ~256 MB); all bases 64B-aligned
    int*          cursor = (int*)d_ws;                       // 512
    float*        dinv   = (float*)(cursor + 512);           // N (pad 100352)
    __half*       h1h    = (__half*)(dinv + 100352);         // N*16 halves, 3.2 MB
    float2*       h2f    = (float2*)(h1h + (size_t)100352 * H1);  // N float2
    unsigned int* eop    = (unsigned int*)(h2f + 100352);    // NB*CAP = 20.4 MB

    k_zero     <<<1,      512, 0, stream>>>(cursor);
    k_partition<<<PBLK,   512, 0, stream>>>(ei, cursor, eop);
    k_count    <<<NB * 2, 512, 0, stream>>>(cursor, eop, dinv);
    k_mm1      <<<(N_NODES + MROWS - 1) / MROWS, 256, 0, stream>>>(x, W1, dinv, h1h);
    k_agg1f    <<<NB * 2, 512, 0, stream>>>(cursor, eop, h1h, dinv, b1, W2, h2f);
    k_agg2f    <<<NB * 2, 512, 0, stream>>>(cursor, eop, h2f, dinv, b2, out);
}

// Round 12
// 225.035 us; speedup vs baseline: 1.1029x; 1.1029x over previous
//
#include <hip/hip_runtime.h>
#include <hip/hip_fp16.h>
#include <math.h>

#define N_NODES 100000
#define N_EDGES 3200000
#define D_IN    128
#define H1      16

#define BSH     8
#define NPB     256                    // nodes per bucket (partition granularity)
#define NB      391                    // ceil(100000/256)
#define CAP     13056                  // eop region capacity (x16; padded fill ~12280)
#define PBLK    512
#define CHUNK   6250                   // N_EDGES / PBLK exact
#define ELS_CAP 12128                  // >= 6250 + 391*15 = 12115, multiple of 16
#define NLINES  (ELS_CAP / 16)         // 758
#define MROWS   64
#define AELS    5120                   // sorted-src LDS cap per half (mean 4096 + 16 sigma)

// eop: NB regions of CAP uints holding packed (src<<8|dloc), runs padded to 64B
// lines with 0xFFFFFFFF sentinels, written as full lines (round-8 fix).
// k_count persists per-node degree + exclusive offset (gdeg/goff) so k_agg1f
// does ONE region pass (scatter to LDS) then aggregates with 4 lanes/node.

union H4 { uint2 u; __half2 h[2]; };

__global__ __launch_bounds__(512) void k_zero(int* __restrict__ cursor) {
    int t = threadIdx.x;
    if (t < NB) cursor[t] = 0;
}

// ---- partition: rank -> scan -> LDS bucket-sort -> coalesced full-line writeout ----
__global__ __launch_bounds__(512) void k_partition(const int* __restrict__ ei,
                                                   int* __restrict__ cursor,
                                                   unsigned int* __restrict__ eop) {
    __shared__ int h[512];                       // per-bucket counts (pad to 512)
    __shared__ int loff[512];                    // scan -> exclusive local offsets
    __shared__ int resv[NB];                     // global region offsets
    __shared__ unsigned short owner[NLINES];     // line -> bucket
    __shared__ unsigned char rank8[CHUNK];       // per-edge rank in its run (<255)
    __shared__ unsigned int els[ELS_CAP];        // 48.5 KB staging
    int t = threadIdx.x;
    h[t] = 0;
    __syncthreads();
    int c0 = blockIdx.x * CHUNK;
    const int* srcs = ei + c0;
    const int* dsts = ei + N_EDGES + c0;
    for (int i = t; i < CHUNK; i += 512)
        rank8[i] = (unsigned char)atomicAdd(&h[dsts[i] >> BSH], 1);
    __syncthreads();
    int cp = (h[t] + 15) & ~15;                  // run padded to 64B multiple
    loff[t] = cp;
    __syncthreads();
    for (int o = 1; o < 512; o <<= 1) {          // inclusive Hillis-Steele
        int u = (t >= o) ? loff[t - o] : 0;
        __syncthreads();
        loff[t] += u;
        __syncthreads();
    }
    int inc = loff[t];
    int totalpad = loff[511];                    // <= ELS_CAP by construction
    int ex = inc - cp;
    __syncthreads();
    loff[t] = ex;                                // now exclusive
    if (t < NB && cp) {
        resv[t] = atomicAdd(&cursor[t], cp);     // stays 16-aligned
        int l0 = ex >> 4;
        for (int k = 0; k < (cp >> 4); ++k) owner[l0 + k] = (unsigned short)t;
    }
    for (int i = t; i < totalpad; i += 512) els[i] = 0xFFFFFFFFu;   // sentinels
    __syncthreads();
    for (int i = t; i < CHUNK; i += 512) {       // LDS bucket-sort scatter
        int s = srcs[i];
        int d = dsts[i];
        int b = d >> BSH;
        els[loff[b] + (int)rank8[i]] = ((unsigned)s << BSH) | (unsigned)(d & (NPB - 1));
    }
    __syncthreads();
    for (int i = t; i < totalpad; i += 512) {    // coalesced: full 64B lines
        int b   = owner[i >> 4];
        int pos = resv[b] + (i - loff[b]);
        if (pos < CAP)                           // statistically impossible guard
            eop[(size_t)b * CAP + pos] = els[i];
    }
}

// ---- count: half-bucket degree + exclusive offset -> dinv, gdeg, goff ----
__global__ __launch_bounds__(512) void k_count(const int* __restrict__ cursor,
                                               const unsigned int* __restrict__ eop,
                                               float* __restrict__ dinv,
                                               int* __restrict__ gdeg,
                                               int* __restrict__ goff) {
    __shared__ int cnt[128], off[128];
    int t = threadIdx.x;
    int b = blockIdx.x >> 1, hh = blockIdx.x & 1;
    if (t < 128) cnt[t] = 0;
    __syncthreads();
    int n = cursor[b]; if (n > CAP) n = CAP;     // multiple of 16
    const uint4* reg4 = (const uint4*)(eop + (size_t)b * CAP);
    for (int i = t; i < (n >> 2); i += 512) {
        uint4 v = reg4[i];
        if ((int)v.x >= 0 && (((v.x & (NPB-1)) >> 7) == (unsigned)hh)) atomicAdd(&cnt[v.x & 127], 1);
        if ((int)v.y >= 0 && (((v.y & (NPB-1)) >> 7) == (unsigned)hh)) atomicAdd(&cnt[v.y & 127], 1);
        if ((int)v.z >= 0 && (((v.z & (NPB-1)) >> 7) == (unsigned)hh)) atomicAdd(&cnt[v.z & 127], 1);
        if ((int)v.w >= 0 && (((v.w & (NPB-1)) >> 7) == (unsigned)hh)) atomicAdd(&cnt[v.w & 127], 1);
    }
    __syncthreads();
    int val = (t < 128) ? cnt[t] : 0;
    if (t < 128) off[t] = val;
    __syncthreads();
    for (int o = 1; o < 128; o <<= 1) {          // inclusive Hillis-Steele
        int u = 0;
        if (t < 128 && t >= o) u = off[t - o];
        __syncthreads();
        if (t < 128) off[t] += u;
        __syncthreads();
    }
    if (t < 128) {
        int node = (b << BSH) + (hh << 7) + t;
        if (node < N_NODES) dinv[node] = rsqrtf((float)(val + 1));   // +1 self-loop
        gdeg[blockIdx.x * 128 + t] = val;
        goff[blockIdx.x * 128 + t] = off[t] - val;   // exclusive
    }
}

// ---- matmul: wave = 64 rows x 4 cols, x in LDS (pad 129), W uniform loads ----
__global__ __launch_bounds__(256) void k_mm1(const float* __restrict__ x,
                                             const float* __restrict__ W1,
                                             const float* __restrict__ dinv,
                                             __half* __restrict__ h1h) {
    __shared__ float sX[MROWS][D_IN + 1];   // 33 KB
    int t = threadIdx.x;
    int r0 = blockIdx.x * MROWS;
    for (int i = t; i < MROWS * (D_IN / 4); i += 256) {
        int row = i >> 5, c4 = i & 31;
        int grow = r0 + row;
        float4 v = (grow < N_NODES) ? ((const float4*)x)[(size_t)grow * 32 + c4]
                                    : make_float4(0.f, 0.f, 0.f, 0.f);
        sX[row][c4 * 4 + 0] = v.x; sX[row][c4 * 4 + 1] = v.y;
        sX[row][c4 * 4 + 2] = v.z; sX[row][c4 * 4 + 3] = v.w;
    }
    __syncthreads();
    int lane = t & 63;
    int c0 = __builtin_amdgcn_readfirstlane((t >> 6) * 4);
    float a0 = 0.f, a1 = 0.f, a2 = 0.f, a3 = 0.f;
#pragma unroll 4
    for (int d = 0; d < D_IN; ++d) {
        float xv = sX[lane][d];
        a0 = fmaf(xv, W1[d * 16 + c0 + 0], a0);
        a1 = fmaf(xv, W1[d * 16 + c0 + 1], a1);
        a2 = fmaf(xv, W1[d * 16 + c0 + 2], a2);
        a3 = fmaf(xv, W1[d * 16 + c0 + 3], a3);
    }
    int grow = r0 + lane;
    if (grow < N_NODES) {
        float di = dinv[grow];
        __half2* o = (__half2*)(h1h + (size_t)grow * H1 + c0);
        o[0] = __floats2half2_rn(a0 * di, a1 * di);
        o[1] = __floats2half2_rn(a2 * di, a3 * di);
    }
}

// ---- fused sort+agg1: one region pass -> sorted LDS; 4 lanes/node aggregate ----
__global__ __launch_bounds__(512) void k_agg1f(const int* __restrict__ cursor,
                                               const unsigned int* __restrict__ eop,
                                               const int* __restrict__ gdeg,
                                               const int* __restrict__ goff,
                                               const __half* __restrict__ h1h,
                                               const float* __restrict__ dinv,
                                               const float* __restrict__ b1,
                                               const float* __restrict__ W2,
                                               float2* __restrict__ h2f) {
    __shared__ int cnt[128], off[128], cur[128];
    __shared__ int els[AELS];            // sorted src list, 20 KB
    int t = threadIdx.x;
    int b = blockIdx.x >> 1, hh = blockIdx.x & 1;
    if (t < 128) {
        int c = gdeg[blockIdx.x * 128 + t];
        int o = goff[blockIdx.x * 128 + t];
        cnt[t] = c; off[t] = o; cur[t] = o;
    }
    __syncthreads();
    int n = cursor[b]; if (n > CAP) n = CAP;
    const uint4* reg4 = (const uint4*)(eop + (size_t)b * CAP);
    for (int i = t; i < (n >> 2); i += 512) {    // single pass: scatter into LDS
        uint4 v = reg4[i];
#pragma unroll
        for (int k = 0; k < 4; ++k) {
            unsigned int w = (k == 0) ? v.x : (k == 1) ? v.y : (k == 2) ? v.z : v.w;
            if ((int)w >= 0) {
                int dloc = w & (NPB - 1);
                if ((dloc >> 7) == hh) {
                    int r = atomicAdd(&cur[dloc & 127], 1);
                    if (r < AELS) els[r] = w >> 8;
                }
            }
        }
    }
    __syncthreads();
    // aggregation: 128 groups x 4 lanes; lane l holds features 4l..4l+3
    int g = t >> 2, l = t & 3;
    int node = (b << BSH) + (hh << 7) + g;
    if (node >= N_NODES) return;
    int e = cnt[g], base = off[g];
    float a0 = 0.f, a1 = 0.f, a2 = 0.f, a3 = 0.f;
    int j = 0;
    for (; j + 4 <= e; j += 4) {
        int s0 = els[base + j],     s1 = els[base + j + 1];
        int s2 = els[base + j + 2], s3 = els[base + j + 3];
        H4 m0, m1, m2, m3;
        m0.u = ((const uint2*)(h1h + s0 * H1))[l];
        m1.u = ((const uint2*)(h1h + s1 * H1))[l];
        m2.u = ((const uint2*)(h1h + s2 * H1))[l];
        m3.u = ((const uint2*)(h1h + s3 * H1))[l];
        a0 += __low2float(m0.h[0]) + __low2float(m1.h[0]) + __low2float(m2.h[0]) + __low2float(m3.h[0]);
        a1 += __high2float(m0.h[0]) + __high2float(m1.h[0]) + __high2float(m2.h[0]) + __high2float(m3.h[0]);
        a2 += __low2float(m0.h[1]) + __low2float(m1.h[1]) + __low2float(m2.h[1]) + __low2float(m3.h[1]);
        a3 += __high2float(m0.h[1]) + __high2float(m1.h[1]) + __high2float(m2.h[1]) + __high2float(m3.h[1]);
    }
    for (; j < e; ++j) {
        H4 m; m.u = ((const uint2*)(h1h + els[base + j] * H1))[l];
        a0 += __low2float(m.h[0]); a1 += __high2float(m.h[0]);
        a2 += __low2float(m.h[1]); a3 += __high2float(m.h[1]);
    }
    H4 sf; sf.u = ((const uint2*)(h1h + node * H1))[l];   // self-loop msg
    a0 += __low2float(sf.h[0]); a1 += __high2float(sf.h[0]);
    a2 += __low2float(sf.h[1]); a3 += __high2float(sf.h[1]);
    float di = dinv[node];
    int f = 4 * l;
    float h0 = fmaxf(fmaf(di, a0, b1[f + 0]), 0.f);
    float h1v = fmaxf(fmaf(di, a1, b1[f + 1]), 0.f);
    float h2 = fmaxf(fmaf(di, a2, b1[f + 2]), 0.f);
    float h3 = fmaxf(fmaf(di, a3, b1[f + 3]), 0.f);
    float p0 = h0 * W2[2*f] + h1v * W2[2*f+2] + h2 * W2[2*f+4] + h3 * W2[2*f+6];
    float p1 = h0 * W2[2*f+1] + h1v * W2[2*f+3] + h2 * W2[2*f+5] + h3 * W2[2*f+7];
    p0 += __shfl_xor(p0, 1); p1 += __shfl_xor(p1, 1);
    p0 += __shfl_xor(p0, 2); p1 += __shfl_xor(p1, 2);
    if (l == 0) h2f[node] = make_float2(p0 * di, p1 * di);
}

// ---- layer-2 agg: region-direct LDS accumulate + b2 + log_softmax ----
__global__ __launch_bounds__(512) void k_agg2f(const int* __restrict__ cursor,
                                               const unsigned int* __restrict__ eop,
                                               const float2* __restrict__ h2f,
                                               const float* __restrict__ dinv,
                                               const float* __restrict__ b2,
                                               float* __restrict__ out) {
    __shared__ float ax[128], ay[128];
    int t = threadIdx.x;
    int b = blockIdx.x >> 1, hh = blockIdx.x & 1;
    if (t < 128) { ax[t] = 0.f; ay[t] = 0.f; }
    __syncthreads();
    int n = cursor[b]; if (n > CAP) n = CAP;
    const uint4* reg4 = (const uint4*)(eop + (size_t)b * CAP);
    for (int i = t; i < (n >> 2); i += 512) {
        uint4 v = reg4[i];
#pragma unroll
        for (int k = 0; k < 4; ++k) {
            unsigned int w = (k == 0) ? v.x : (k == 1) ? v.y : (k == 2) ? v.z : v.w;
            if ((int)w >= 0) {
                int dloc = w & (NPB - 1);
                if ((dloc >> 7) == hh) {
                    float2 m = h2f[w >> 8];
                    atomicAdd(&ax[dloc & 127], m.x);
                    atomicAdd(&ay[dloc & 127], m.y);
                }
            }
        }
    }
    __syncthreads();
    if (t < 128) {
        int node = (b << BSH) + (hh << 7) + t;
        if (node < N_NODES) {
            float di = dinv[node];
            float2 self = h2f[node];
            float a0 = fmaf(di, ax[t] + self.x, b2[0]);
            float a1 = fmaf(di, ay[t] + self.y, b2[1]);
            float m  = fmaxf(a0, a1);
            float lg = logf(expf(a0 - m) + expf(a1 - m));
            out[2 * node]     = a0 - m - lg;
            out[2 * node + 1] = a1 - m - lg;
        }
    }
}

extern "C" void kernel_launch(void* const* d_in, const int* in_sizes, int n_in,
                              void* d_out, int out_size, void* d_ws, size_t ws_size,
                              hipStream_t stream) {
    const float* x  = (const float*)d_in[0];
    const int*   ei = (const int*)d_in[1];
    const float* W1 = (const float*)d_in[2];
    const float* b1 = (const float*)d_in[3];
    const float* W2 = (const float*)d_in[4];
    const float* b2 = (const float*)d_in[5];
    float* out = (float*)d_out;

    // workspace carve (~26 MB of ~256 MB); all bases 64B-aligned
    int*          cursor = (int*)d_ws;                       // 512
    float*        dinv   = (float*)(cursor + 512);           // N (pad 100352)
    int*          gdeg   = (int*)(dinv + 100352);            // 782*128 (pad 100352)
    int*          goff   = gdeg + 100352;                    // 782*128 (pad 100352)
    __half*       h1h    = (__half*)(goff + 100352);         // N*16 halves, 3.2 MB
    float2*       h2f    = (float2*)(h1h + (size_t)100352 * H1);  // N float2
    unsigned int* eop    = (unsigned int*)(h2f + 100352);    // NB*CAP = 20.4 MB

    k_zero     <<<1,      512, 0, stream>>>(cursor);
    k_partition<<<PBLK,   512, 0, stream>>>(ei, cursor, eop);
    k_count    <<<NB * 2, 512, 0, stream>>>(cursor, eop, dinv, gdeg, goff);
    k_mm1      <<<(N_NODES + MROWS - 1) / MROWS, 256, 0, stream>>>(x, W1, dinv, h1h);
    k_agg1f    <<<NB * 2, 512, 0, stream>>>(cursor, eop, gdeg, goff, h1h, dinv, b1, W2, h2f);
    k_agg2f    <<<NB * 2, 512, 0, stream>>>(cursor, eop, h2f, dinv, b2, out);
}